// Round 8
// baseline (501.487 us; speedup 1.0000x reference)
//
#include <hip/hip_runtime.h>

using bf16x8 = __attribute__((ext_vector_type(8))) short;
using f32x4  = __attribute__((ext_vector_type(4))) float;
using u16 = unsigned short;
using u32 = unsigned int;

// ---------- helpers ----------
__device__ __forceinline__ u16 f2bf(float f) {          // RNE float->bf16
  u32 u = __float_as_uint(f);
  u += 0x7fffu + ((u >> 16) & 1u);
  return (u16)(u >> 16);
}
__device__ __forceinline__ float bf2f(u16 h) {
  return __uint_as_float(((u32)h) << 16);
}
__device__ __forceinline__ uint4 pack8(const u16* h) {
  uint4 r;
  r.x = (u32)h[0] | ((u32)h[1] << 16);
  r.y = (u32)h[2] | ((u32)h[3] << 16);
  r.z = (u32)h[4] | ((u32)h[5] << 16);
  r.w = (u32)h[6] | ((u32)h[7] << 16);
  return r;
}
__device__ __forceinline__ float gelu_fast(float x) {   // == 0.5x(1+tanh(u)) exactly
  float u2 = 1.5957691216057308f * (x + 0.044715f * x * x * x);  // 2u
  return x / (1.0f + __expf(-u2));
}
__device__ __forceinline__ void gload16(const void* g, void* l) {
  __builtin_amdgcn_global_load_lds(
      (const __attribute__((address_space(1))) void*)g,
      (__attribute__((address_space(3))) void*)l, 16, 0, 0);
}

// ---------- weight transpose: [R,C] f32 -> [C,R] bf16 (hi, optional lo) ----------
__global__ __launch_bounds__(256) void transpose_split_kernel(
    const float* __restrict__ in, u16* __restrict__ outH, u16* __restrict__ outL,
    int R, int C)
{
  __shared__ float t[32][33];
  const int lx = threadIdx.x & 31, ly = threadIdx.x >> 5;
  const int c0 = blockIdx.x << 5, r0 = blockIdx.y << 5;
  for (int i = ly; i < 32; i += 8)
    t[i][lx] = in[(long)(r0 + i) * C + c0 + lx];
  __syncthreads();
  for (int i = ly; i < 32; i += 8) {
    float v = t[lx][i];
    long o = (long)(c0 + i) * R + r0 + lx;
    u16 h = f2bf(v);
    outH[o] = h;
    if (outL) outL[o] = f2bf(v - bf2f(h));
  }
}

// ---------- LayerNorm over rows of 512 f32, out bf16 hi (+ optional lo) ----------
__global__ __launch_bounds__(256) void ln_split_kernel(
    const float* __restrict__ x, const float* __restrict__ gamma,
    const float* __restrict__ beta, u16* __restrict__ outH, u16* __restrict__ outL)
{
  const int row  = (blockIdx.x << 2) + (threadIdx.x >> 6);
  const int lane = threadIdx.x & 63;
  const float* xr = x + (long)row * 512 + lane * 8;
  float v[8];
  *(float4*)&v[0] = *(const float4*)xr;
  *(float4*)&v[4] = *(const float4*)(xr + 4);
  float s = 0.f;
#pragma unroll
  for (int j = 0; j < 8; ++j) s += v[j];
#pragma unroll
  for (int o = 32; o; o >>= 1) s += __shfl_xor(s, o);
  const float mu = s * (1.0f / 512.0f);
  float q = 0.f;
#pragma unroll
  for (int j = 0; j < 8; ++j) { float d = v[j] - mu; q += d * d; }
#pragma unroll
  for (int o = 32; o; o >>= 1) q += __shfl_xor(q, o);
  const float rs = rsqrtf(q * (1.0f / 512.0f) + 1e-5f);
  float gv[8], bv[8];
  *(float4*)&gv[0] = *(const float4*)(gamma + lane * 8);
  *(float4*)&gv[4] = *(const float4*)(gamma + lane * 8 + 4);
  *(float4*)&bv[0] = *(const float4*)(beta + lane * 8);
  *(float4*)&bv[4] = *(const float4*)(beta + lane * 8 + 4);
  u16 hs[8], ls[8];
#pragma unroll
  for (int j = 0; j < 8; ++j) {
    float y = (v[j] - mu) * rs * gv[j] + bv[j];
    hs[j] = f2bf(y);
    ls[j] = f2bf(y - bf2f(hs[j]));
  }
  *(uint4*)(outH + (long)row * 512 + lane * 8) = pack8(hs);
  if (outL) *(uint4*)(outL + (long)row * 512 + lane * 8) = pack8(ls);
}

// ---------- row softmax over 512 f32 -> bf16 ----------
__global__ __launch_bounds__(256) void softmax_kernel(
    const float* __restrict__ scores, u16* __restrict__ attn)
{
  const int row  = (blockIdx.x << 2) + (threadIdx.x >> 6);
  const int lane = threadIdx.x & 63;
  const float* sr = scores + (long)row * 512 + lane * 8;
  float v[8];
  *(float4*)&v[0] = *(const float4*)sr;
  *(float4*)&v[4] = *(const float4*)(sr + 4);
  float m = v[0];
#pragma unroll
  for (int j = 1; j < 8; ++j) m = fmaxf(m, v[j]);
#pragma unroll
  for (int o = 32; o; o >>= 1) m = fmaxf(m, __shfl_xor(m, o));
  float e[8], s = 0.f;
#pragma unroll
  for (int j = 0; j < 8; ++j) { e[j] = __expf(v[j] - m); s += e[j]; }
#pragma unroll
  for (int o = 32; o; o >>= 1) s += __shfl_xor(s, o);
  const float inv = 1.0f / s;
  u16 h[8];
#pragma unroll
  for (int j = 0; j < 8; ++j) h[j] = f2bf(e[j] * inv);
  *(uint4*)(attn + (long)row * 512 + lane * 8) = pack8(h);
}

// ---------- 128x128 4-wave NT GEMM, BK=64 — occupancy play (5 blocks/CU) ----
// C[m,n] = sum_k A[m,k]*B[n,k]. K in NT tiles of 64; tile t uses part (t>>3)
// (hi/lo K-concatenation for split-precision GEMMs without materializing).
// LDS: ONE 32KB buffer: A[128][64] bf16 at 0 (rows 128B, 16B slot s of row r
// stored at position s^(r&7)); B same at +16KB. 5 blocks/CU co-resident
// (32KB of 160KB) -> 20 waves/CU: staging latency of one block hides under
// the other blocks' MFMA (m114/m97 mechanism — the HW-verified path, vs the
// 1-block/CU 256^2 structure of r2-r7 that pinned MfmaUtil at ~25%).
// Per K-tile (m97's exact 2-barrier pattern, no asm, no prefetch):
//   __syncthreads(); 8x global_load_lds (A 4, B 4);
//   __syncthreads() [native vmcnt0 drain + publish];
//   16x ds_read_b128 + 32x MFMA.
// Swapped-operand MFMA (mfma(B,A)): lane's acc quad = 4 consecutive N cols.
// XCD-chunked block swizzle keeps panel-sharing blocks on one XCD's L2.
// EPI: 0 bf16 sqrt(v^2+eps); 1 split hi/lo; 2 f32 sqrt(v^2+eps); 3 resid+v;
//      4 gelu(v+bias) bf16; 5 resid+v+bias.
template<int EPI>
__global__ __launch_bounds__(256) void gemm8(
    const char* A0, const char* A1, const char* A2, const char* A3,
    const char* B0, const char* B1, const char* B2, const char* B3,
    int N, int NT, int ldAb, int ldBb,
    long sAb, long sBb, long sC,
    float* __restrict__ outF, u16* __restrict__ outU, u16* __restrict__ outU2,
    const float* __restrict__ resid, const float* __restrict__ bias)
{
  __shared__ __align__(16) char lds[32768];
  const int tid = threadIdx.x;
  const int w = tid >> 6, l = tid & 63;
  const int wr = w >> 1, wc = w & 1;

  // XCD-chunked block swizzle (total %8 == 0 for all our launches)
  const int gx = gridDim.x, gy = gridDim.y;
  int flat = ((int)blockIdx.z * gy + (int)blockIdx.y) * gx + (int)blockIdx.x;
  const int total = gx * gy * (int)gridDim.z;
  flat = (flat & 7) * (total >> 3) + (flat >> 3);
  const int bx = flat % gx;
  int rem = flat / gx;
  const int by = rem % gy, bz = rem / gy;

  const long blockM = (long)by * 128;
  const long blockN = (long)bx * 128;
  const long za = (long)bz * sAb;
  const long zb = (long)bz * sBb;
  const char* a0p = A0 + za; const char* a1p = A1 + za;
  const char* a2p = A2 + za; const char* a3p = A3 + za;
  const char* b0p = B0 + zb; const char* b1p = B1 + zb;
  const char* b2p = B2 + zb; const char* b3p = B3 + zb;

  auto partA = [&](int t) { return t < 8 ? a0p : t < 16 ? a1p : t < 24 ? a2p : a3p; };
  auto partB = [&](int t) { return t < 8 ? b0p : t < 16 ? b1p : t < 24 ? b2p : b3p; };

  // staging: thread tid covers rows (tid>>3)+32g, g=0..3, slot (tid&7);
  // global source slot pre-swizzled: (tid&7)^((tid>>3)&7) so the LDS-linear
  // destination (slot tid&7 of row) holds swizzled content.
  const long stgSw = ((tid & 7) ^ ((tid >> 3) & 7)) << 4;
  const long raA = (blockM + (tid >> 3)) * (long)ldAb + stgSw;
  const long raB = (blockN + (tid >> 3)) * (long)ldBb + stgSw;
  auto stageA = [&](int t) {
    const char* s = partA(t) + (((long)(t & 7)) << 7) + raA;
#pragma unroll
    for (int g = 0; g < 4; ++g)
      gload16(s + (long)g * 32 * ldAb, lds + g * 4096 + (tid << 4));
  };
  auto stageB = [&](int t) {
    const char* s = partB(t) + (((long)(t & 7)) << 7) + raB;
#pragma unroll
    for (int g = 0; g < 4; ++g)
      gload16(s + (long)g * 32 * ldBb, lds + 16384 + g * 4096 + (tid << 4));
  };

  f32x4 acc[4][4];
#pragma unroll
  for (int i = 0; i < 4; ++i)
#pragma unroll
    for (int j = 0; j < 4; ++j) acc[i][j] = (f32x4){0.f, 0.f, 0.f, 0.f};

  const int lr = l & 15, kg = l >> 4;
  // slot for k-half kh = (kh*4 + kg) ^ (lr&7); row byte = row*128
  const int sl0 = ((kg) ^ (lr & 7)) << 4;
  const int sl1 = ((4 + kg) ^ (lr & 7)) << 4;
  const char* aL = lds + (wr << 13) + (lr << 7);           // + mf*2048 + slot
  const char* bL = lds + 16384 + (wc << 13) + (lr << 7);   // + nf*2048 + slot

  bf16x8 a[4][2], b[4][2];

#define MFMA32()                                                              \
  do {                                                                        \
    _Pragma("unroll")                                                         \
    for (int kh = 0; kh < 2; ++kh)                                            \
      _Pragma("unroll")                                                       \
      for (int mf = 0; mf < 4; ++mf)                                          \
        _Pragma("unroll")                                                     \
        for (int nf = 0; nf < 4; ++nf)                                        \
          acc[mf][nf] = __builtin_amdgcn_mfma_f32_16x16x32_bf16(              \
              b[nf][kh], a[mf][kh], acc[mf][nf], 0, 0, 0);                    \
  } while (0)

  for (int t = 0; t < NT; ++t) {
    __syncthreads();            // all waves done reading previous tile
    stageA(t); stageB(t);       // 8 global_load_lds
    __syncthreads();            // native vmcnt(0) drain + publish
#pragma unroll
    for (int mf = 0; mf < 4; ++mf) {
      a[mf][0] = *(const bf16x8*)(aL + (mf << 11) + sl0);
      a[mf][1] = *(const bf16x8*)(aL + (mf << 11) + sl1);
    }
#pragma unroll
    for (int nf = 0; nf < 4; ++nf) {
      b[nf][0] = *(const bf16x8*)(bL + (nf << 11) + sl0);
      b[nf][1] = *(const bf16x8*)(bL + (nf << 11) + sl1);
    }
    MFMA32();
  }
#undef MFMA32

  // ---- epilogue (swapped layout): m = ..+lr, n = ..+kg*4+r -> wide stores
  const long cb = (long)bz * sC;
  const int m0 = (int)blockM + wr * 64 + lr;
  const int n0 = (int)blockN + wc * 64 + (kg << 2);
#pragma unroll
  for (int mi = 0; mi < 4; ++mi)
#pragma unroll
    for (int ni = 0; ni < 4; ++ni) {
      const int m = m0 + (mi << 4);
      const int n = n0 + (ni << 4);
      const long idx = cb + (long)m * N + n;
      f32x4 v = acc[mi][ni];
      if (EPI == 0) {
        union { u16 h[4]; uint2 u; } p;
#pragma unroll
        for (int r = 0; r < 4; ++r) p.h[r] = f2bf(sqrtf(v[r] * v[r] + 1e-8f));
        *(uint2*)(outU + idx) = p.u;
      } else if (EPI == 1) {
        union { u16 h[4]; uint2 u; } ph, pl;
#pragma unroll
        for (int r = 0; r < 4; ++r) {
          ph.h[r] = f2bf(v[r]);
          pl.h[r] = f2bf(v[r] - bf2f(ph.h[r]));
        }
        *(uint2*)(outU + idx) = ph.u;
        *(uint2*)(outU2 + idx) = pl.u;
      } else if (EPI == 2) {
        f32x4 o;
#pragma unroll
        for (int r = 0; r < 4; ++r) o[r] = sqrtf(v[r] * v[r] + 1e-8f);
        *(f32x4*)(outF + idx) = o;
      } else if (EPI == 3) {
        f32x4 rd = *(const f32x4*)(resid + idx);
#pragma unroll
        for (int r = 0; r < 4; ++r) rd[r] += v[r];
        *(f32x4*)(outF + idx) = rd;
      } else if (EPI == 4) {
        f32x4 bb = *(const f32x4*)(bias + n);
        union { u16 h[4]; uint2 u; } p;
#pragma unroll
        for (int r = 0; r < 4; ++r) p.h[r] = f2bf(gelu_fast(v[r] + bb[r]));
        *(uint2*)(outU + idx) = p.u;
      } else {
        f32x4 rd = *(const f32x4*)(resid + idx);
        f32x4 bb = *(const f32x4*)(bias + n);
#pragma unroll
        for (int r = 0; r < 4; ++r) rd[r] += v[r] + bb[r];
        *(f32x4*)(outF + idx) = rd;
      }
    }
}

// ---------- launch ----------
extern "C" void kernel_launch(void* const* d_in, const int* in_sizes, int n_in,
                              void* d_out, int out_size, void* d_ws, size_t ws_size,
                              hipStream_t stream)
{
  const float* x   = (const float*)d_in[0];
  const float* g1  = (const float*)d_in[1];
  const float* be1 = (const float*)d_in[2];
  const float* Wv  = (const float*)d_in[3];
  const float* Ww  = (const float*)d_in[4];
  const float* g2  = (const float*)d_in[5];
  const float* be2 = (const float*)d_in[6];
  const float* W1  = (const float*)d_in[7];
  const float* b1  = (const float*)d_in[8];
  const float* W2  = (const float*)d_in[9];
  const float* b2  = (const float*)d_in[10];
  float* out = (float*)d_out;

  char* ws = (char*)d_ws;
  // B=64, T=E=512, H=2048, M=B*T=32768. Lifetimes allow heavy aliasing.
  u16* inp_hi  = (u16*)(ws);                 // [0,32M)   LN1 -> vx-GEMM
  u16* inp_lo  = (u16*)(ws + 33554432);      // [32,64M)  LN1 -> scores
  u16* proj_hi = (u16*)(ws + 67108864);      // [64,96M)  proj -> scores
  u16* proj_lo = (u16*)(ws + 100663296);     // [96,128M) proj -> scores
  float* scores= (float*)(ws + 134217728);   // [128,192M) scores -> softmax
  u16* attn    = proj_hi;                    // alias: written after proj dead
  u16* vx      = proj_lo;                    // alias: vx-GEMM runs post-softmax
  u16* h_in    = inp_hi;                     // alias: written after inp dead
  u16* h_mid   = (u16*)(ws + 33554432);      // [32,160M): all dead by MLP1
  char* wb = ws + 201326592;                 // weights live whole run
  u16* WvT  = (u16*)(wb);
  u16* WwTh = (u16*)(wb + 524288);
  u16* WwTl = (u16*)(wb + 1048576);
  u16* W1T  = (u16*)(wb + 1572864);
  u16* W2T  = (u16*)(wb + 3670016);
  // total ws used: ~207.1 MB

  // weight transposes (f32 -> bf16, K-contiguous for NT GEMM)
  transpose_split_kernel<<<dim3(16, 16), 256, 0, stream>>>(Wv, WvT, nullptr, 512, 512);
  transpose_split_kernel<<<dim3(16, 16), 256, 0, stream>>>(Ww, WwTh, WwTl, 512, 512);
  transpose_split_kernel<<<dim3(64, 16), 256, 0, stream>>>(W1, W1T, nullptr, 512, 2048);
  transpose_split_kernel<<<dim3(16, 64), 256, 0, stream>>>(W2, W2T, nullptr, 2048, 512);

  // LN1: x -> inp hi/lo
  ln_split_kernel<<<8192, 256, 0, stream>>>(x, g1, be1, inp_hi, inp_lo);

  // proj = inp@Ww, split 3-term via K-cat: [ih,il,ih] . [Wh,Wh,Wl], K'=1536
  gemm8<1><<<dim3(4, 256, 1), 256, 0, stream>>>(
      (const char*)inp_hi, (const char*)inp_lo, (const char*)inp_hi, (const char*)inp_hi,
      (const char*)WwTh, (const char*)WwTh, (const char*)WwTl, (const char*)WwTl,
      512, 24, 1024, 1024, 0, 0, 0,
      nullptr, proj_hi, proj_lo, nullptr, nullptr);

  // scores[b,i,j] = sqrt((proj_i . inp_j)^2+eps), split: [ph,ph,pl].[ih,il,ih]
  gemm8<2><<<dim3(4, 4, 64), 256, 0, stream>>>(
      (const char*)proj_hi, (const char*)proj_hi, (const char*)proj_lo, (const char*)proj_lo,
      (const char*)inp_hi, (const char*)inp_lo, (const char*)inp_hi, (const char*)inp_hi,
      512, 24, 1024, 1024, 524288, 524288, 262144,
      scores, nullptr, nullptr, nullptr, nullptr);

  // softmax rows -> attn bf16 (into dead proj_hi)
  softmax_kernel<<<8192, 256, 0, stream>>>(scores, attn);

  // vx = sqrt((inp@Wv)^2+eps) (into dead proj_lo)
  gemm8<0><<<dim3(4, 256, 1), 256, 0, stream>>>(
      (const char*)inp_hi, (const char*)inp_hi, (const char*)inp_hi, (const char*)inp_hi,
      (const char*)WvT, (const char*)WvT, (const char*)WvT, (const char*)WvT,
      512, 8, 1024, 1024, 0, 0, 0,
      nullptr, vx, nullptr, nullptr, nullptr);

  // x1 = x + attn@vx^T -> d_out (batched)
  gemm8<3><<<dim3(4, 4, 64), 256, 0, stream>>>(
      (const char*)attn, (const char*)attn, (const char*)attn, (const char*)attn,
      (const char*)vx, (const char*)vx, (const char*)vx, (const char*)vx,
      512, 8, 1024, 1024, 524288, 524288, 262144,
      out, nullptr, nullptr, x, nullptr);

  // LN2: x1 -> h_in (bf16 hi only)
  ln_split_kernel<<<8192, 256, 0, stream>>>(out, g2, be2, h_in, nullptr);

  // h_mid = gelu(h_in@W1 + b1)
  gemm8<4><<<dim3(16, 256, 1), 256, 0, stream>>>(
      (const char*)h_in, (const char*)h_in, (const char*)h_in, (const char*)h_in,
      (const char*)W1T, (const char*)W1T, (const char*)W1T, (const char*)W1T,
      2048, 8, 1024, 1024, 0, 0, 0,
      nullptr, h_mid, nullptr, nullptr, b1);

  // out = x1 + h_mid@W2 + b2  (K=2048 via 4 contiguous parts)
  gemm8<5><<<dim3(4, 256, 1), 256, 0, stream>>>(
      (const char*)h_mid, (const char*)h_mid + 1024, (const char*)h_mid + 2048, (const char*)h_mid + 3072,
      (const char*)W2T, (const char*)W2T + 1024, (const char*)W2T + 2048, (const char*)W2T + 3072,
      512, 32, 4096, 4096, 0, 0, 0,
      out, nullptr, nullptr, out, b2);
}

// Round 9
// 474.563 us; speedup vs baseline: 1.0567x; 1.0567x over previous
//
#include <hip/hip_runtime.h>

using bf16x8 = __attribute__((ext_vector_type(8))) short;
using f32x4  = __attribute__((ext_vector_type(4))) float;
using u16 = unsigned short;
using u32 = unsigned int;

// ---------- helpers ----------
__device__ __forceinline__ u16 f2bf(float f) {          // RNE float->bf16
  u32 u = __float_as_uint(f);
  u += 0x7fffu + ((u >> 16) & 1u);
  return (u16)(u >> 16);
}
__device__ __forceinline__ float bf2f(u16 h) {
  return __uint_as_float(((u32)h) << 16);
}
__device__ __forceinline__ uint4 pack8(const u16* h) {
  uint4 r;
  r.x = (u32)h[0] | ((u32)h[1] << 16);
  r.y = (u32)h[2] | ((u32)h[3] << 16);
  r.z = (u32)h[4] | ((u32)h[5] << 16);
  r.w = (u32)h[6] | ((u32)h[7] << 16);
  return r;
}
__device__ __forceinline__ float gelu_fast(float x) {   // == 0.5x(1+tanh(u)) exactly
  float u2 = 1.5957691216057308f * (x + 0.044715f * x * x * x);  // 2u
  return x / (1.0f + __expf(-u2));
}
__device__ __forceinline__ void gload16(const void* g, void* l) {
  __builtin_amdgcn_global_load_lds(
      (const __attribute__((address_space(1))) void*)g,
      (__attribute__((address_space(3))) void*)l, 16, 0, 0);
}

// ---------- weight transpose: [R,C] f32 -> [C,R] bf16 (hi, optional lo) ----------
__global__ __launch_bounds__(256) void transpose_split_kernel(
    const float* __restrict__ in, u16* __restrict__ outH, u16* __restrict__ outL,
    int R, int C)
{
  __shared__ float t[32][33];
  const int lx = threadIdx.x & 31, ly = threadIdx.x >> 5;
  const int c0 = blockIdx.x << 5, r0 = blockIdx.y << 5;
  for (int i = ly; i < 32; i += 8)
    t[i][lx] = in[(long)(r0 + i) * C + c0 + lx];
  __syncthreads();
  for (int i = ly; i < 32; i += 8) {
    float v = t[lx][i];
    long o = (long)(c0 + i) * R + r0 + lx;
    u16 h = f2bf(v);
    outH[o] = h;
    if (outL) outL[o] = f2bf(v - bf2f(h));
  }
}

// ---------- LayerNorm over rows of 512 f32, out bf16 hi (+ optional lo) ----------
__global__ __launch_bounds__(256) void ln_split_kernel(
    const float* __restrict__ x, const float* __restrict__ gamma,
    const float* __restrict__ beta, u16* __restrict__ outH, u16* __restrict__ outL)
{
  const int row  = (blockIdx.x << 2) + (threadIdx.x >> 6);
  const int lane = threadIdx.x & 63;
  const float* xr = x + (long)row * 512 + lane * 8;
  float v[8];
  *(float4*)&v[0] = *(const float4*)xr;
  *(float4*)&v[4] = *(const float4*)(xr + 4);
  float s = 0.f;
#pragma unroll
  for (int j = 0; j < 8; ++j) s += v[j];
#pragma unroll
  for (int o = 32; o; o >>= 1) s += __shfl_xor(s, o);
  const float mu = s * (1.0f / 512.0f);
  float q = 0.f;
#pragma unroll
  for (int j = 0; j < 8; ++j) { float d = v[j] - mu; q += d * d; }
#pragma unroll
  for (int o = 32; o; o >>= 1) q += __shfl_xor(q, o);
  const float rs = rsqrtf(q * (1.0f / 512.0f) + 1e-5f);
  float gv[8], bv[8];
  *(float4*)&gv[0] = *(const float4*)(gamma + lane * 8);
  *(float4*)&gv[4] = *(const float4*)(gamma + lane * 8 + 4);
  *(float4*)&bv[0] = *(const float4*)(beta + lane * 8);
  *(float4*)&bv[4] = *(const float4*)(beta + lane * 8 + 4);
  u16 hs[8], ls[8];
#pragma unroll
  for (int j = 0; j < 8; ++j) {
    float y = (v[j] - mu) * rs * gv[j] + bv[j];
    hs[j] = f2bf(y);
    ls[j] = f2bf(y - bf2f(hs[j]));
  }
  *(uint4*)(outH + (long)row * 512 + lane * 8) = pack8(hs);
  if (outL) *(uint4*)(outL + (long)row * 512 + lane * 8) = pack8(ls);
}

// ---------- 256x256 8-wave NT GEMM, BK=64 (r7 structure, best measured) ----------
// C[m,n] = sum_k A[m,k]*B[n,k]. K in NT tiles of 64; tile t uses part (t>>3).
// EPI: 0 bf16 sqrt(v^2+eps); 1 split hi/lo; 4 gelu(v+bias) bf16; 5 resid+v+bias.
template<int EPI>
__global__ __launch_bounds__(512) void gemm8(
    const char* A0, const char* A1, const char* A2, const char* A3,
    const char* B0, const char* B1, const char* B2, const char* B3,
    int N, int NT, int ldAb, int ldBb,
    long sAb, long sBb, long sC,
    float* __restrict__ outF, u16* __restrict__ outU, u16* __restrict__ outU2,
    const float* __restrict__ resid, const float* __restrict__ bias)
{
  __shared__ __align__(16) char lds[131072];
  const int tid = threadIdx.x;
  const int w = tid >> 6, l = tid & 63;
  const int wm = w >> 2, wn = w & 3;

  // XCD-chunked block swizzle (total %8 == 0 for all our launches)
  const int gx = gridDim.x, gy = gridDim.y;
  int flat = ((int)blockIdx.z * gy + (int)blockIdx.y) * gx + (int)blockIdx.x;
  const int total = gx * gy * (int)gridDim.z;
  flat = (flat & 7) * (total >> 3) + (flat >> 3);
  const int bx = flat % gx;
  int rem = flat / gx;
  const int by = rem % gy, bz = rem / gy;

  const long blockM = (long)by * 256;
  const long blockN = (long)bx * 256;
  const long za = (long)bz * sAb;
  const long zb = (long)bz * sBb;
  const char* a0p = A0 + za; const char* a1p = A1 + za;
  const char* a2p = A2 + za; const char* a3p = A3 + za;
  const char* b0p = B0 + zb; const char* b1p = B1 + zb;
  const char* b2p = B2 + zb; const char* b3p = B3 + zb;

  auto partA = [&](int t) { return t < 8 ? a0p : t < 16 ? a1p : t < 24 ? a2p : a3p; };
  auto partB = [&](int t) { return t < 8 ? b0p : t < 16 ? b1p : t < 24 ? b2p : b3p; };

  const long stgSw = ((tid & 7) ^ ((tid >> 3) & 7)) << 4;
  const long raA = (blockM + (tid >> 3)) * (long)ldAb + stgSw;
  const long raB = (blockN + (tid >> 3)) * (long)ldBb + stgSw;
  auto stageA = [&](int t, int h) {
    const char* s = partA(t) + (((long)(t & 7)) << 7) + raA + (long)h * 128 * ldAb;
    char* dptr = lds + ((t & 1) << 15) + (h << 14) + (tid << 4);
    gload16(s, dptr);
    gload16(s + (long)64 * ldAb, dptr + 8192);
  };
  auto stageB = [&](int t, int h) {
    const char* s = partB(t) + (((long)(t & 7)) << 7) + raB + (long)h * 128 * ldBb;
    char* dptr = lds + 65536 + ((t & 1) << 15) + (h << 14) + (tid << 4);
    gload16(s, dptr);
    gload16(s + (long)64 * ldBb, dptr + 8192);
  };

  f32x4 acc[8][4];
#pragma unroll
  for (int i = 0; i < 8; ++i)
#pragma unroll
    for (int j = 0; j < 4; ++j) acc[i][j] = (f32x4){0.f, 0.f, 0.f, 0.f};

  const int lr = l & 15, kg = l >> 4;
  const int xs = kg ^ (l & 7);
  const int po0 = (lr << 7) + (xs << 4);
  const int po1 = (lr << 7) + ((xs ^ 4) << 4);
  const char* aL = lds + (wm << 14);
  const char* bL = lds + 65536 + ((wn >> 1) << 14) + ((wn & 1) << 13);

  bf16x8 a[4], bk0[4], bk1[4];
  auto readA = [&](const char* p) {
#pragma unroll
    for (int mf = 0; mf < 4; ++mf) a[mf] = *(const bf16x8*)(p + (mf << 11));
  };
  auto readB = [&](bf16x8* d, const char* p) {
#pragma unroll
    for (int nf = 0; nf < 4; ++nf) d[nf] = *(const bf16x8*)(p + (nf << 11));
  };

#define MFMA16(MH, BK)                                                        \
  do {                                                                        \
    _Pragma("unroll")                                                         \
    for (int mf = 0; mf < 4; ++mf)                                            \
      _Pragma("unroll")                                                       \
      for (int nf = 0; nf < 4; ++nf)                                          \
        acc[MH * 4 + mf][nf] = __builtin_amdgcn_mfma_f32_16x16x32_bf16(       \
            BK[nf], a[mf], acc[MH * 4 + mf][nf], 0, 0, 0);                    \
  } while (0)

  stageA(0, 0); stageA(0, 1); stageB(0, 0); stageB(0, 1);
  __syncthreads();

  for (int t = 0; t < NT; ++t) {
    const int d = t & 1;
    const char* aD = aL + (d << 15);
    const char* bD = bL + (d << 15);
    if (t + 1 < NT) {
      stageA(t + 1, 0); stageA(t + 1, 1); stageB(t + 1, 0); stageB(t + 1, 1);
    }
    readA(aD + po0);
    readB(bk0, bD + po0);
    MFMA16(0, bk0);
    readA(aD + po1);
    readB(bk1, bD + po1);
    MFMA16(0, bk1);
    readA(aD + 8192 + po0);
    MFMA16(1, bk0);
    readA(aD + 8192 + po1);
    MFMA16(1, bk1);
    if (t + 1 < NT) __syncthreads();
  }
#undef MFMA16

  const long cb = (long)bz * sC;
  const int m0 = (int)blockM + wm * 128 + lr;
  const int n0 = (int)blockN + wn * 64 + (kg << 2);
#pragma unroll
  for (int mi = 0; mi < 8; ++mi)
#pragma unroll
    for (int ni = 0; ni < 4; ++ni) {
      const int m = m0 + (mi << 4);
      const int n = n0 + (ni << 4);
      const long idx = cb + (long)m * N + n;
      f32x4 v = acc[mi][ni];
      if (EPI == 0) {
        union { u16 h[4]; uint2 u; } p;
#pragma unroll
        for (int r = 0; r < 4; ++r) p.h[r] = f2bf(sqrtf(v[r] * v[r] + 1e-8f));
        *(uint2*)(outU + idx) = p.u;
      } else if (EPI == 1) {
        union { u16 h[4]; uint2 u; } ph, pl;
#pragma unroll
        for (int r = 0; r < 4; ++r) {
          ph.h[r] = f2bf(v[r]);
          pl.h[r] = f2bf(v[r] - bf2f(ph.h[r]));
        }
        *(uint2*)(outU + idx) = ph.u;
        *(uint2*)(outU2 + idx) = pl.u;
      } else if (EPI == 4) {
        f32x4 bb = *(const f32x4*)(bias + n);
        union { u16 h[4]; uint2 u; } p;
#pragma unroll
        for (int r = 0; r < 4; ++r) p.h[r] = f2bf(gelu_fast(v[r] + bb[r]));
        *(uint2*)(outU + idx) = p.u;
      } else {
        f32x4 rd = *(const f32x4*)(resid + idx);
        f32x4 bb = *(const f32x4*)(bias + n);
#pragma unroll
        for (int r = 0; r < 4; ++r) rd[r] += v[r] + bb[r];
        *(f32x4*)(outF + idx) = rd;
      }
    }
}

// ---------- fused row-GEMM: 128x512 tile = full row per block ----------
// C[m,n] = sum_k A[m,k]*B[n,k], batched (z=batch, y=m-tile of 4). K'=NT*64 via
// 3 part pointers (8 tiles each). 8 waves: wm (2) x wn (4); per wave 64 rows x
// 128 cols; per lane acc[4][8] (rows wm*64+mi*16+lr; cols wn*128+nj*16+kg*4+r).
// LDS 80KB: A [128][64] at 0, B [512][64] at 16K; XOR-swizzled (slot^ (row&7)).
// MODE 0: v=sqrt(c^2+eps); row-softmax (shfl over kg + LDS table over wn);
//         write attn bf16. Replaces scores-write + softmax kernel.
// MODE 1: x1 = resid + c -> outF f32; row LayerNorm (same reduction plumbing);
//         h = (x1-mu)*rs*g2+b2 -> outU bf16. Replaces t-GEMM + LN2 kernel.
template<int MODE>
__global__ __launch_bounds__(512) void gemm_row(
    const char* A0, const char* A1, const char* A2,
    const char* B0, const char* B1, const char* B2,
    int NT, long sAb, long sBb,
    u16* __restrict__ outU, float* __restrict__ outF,
    const float* __restrict__ resid,
    const float* __restrict__ g2, const float* __restrict__ b2)
{
  __shared__ __align__(16) char lds[81920];
  const int tid = threadIdx.x;
  const int w = tid >> 6, l = tid & 63;
  const int wm = w >> 2, wn = w & 3;
  const int by = blockIdx.y, bz = blockIdx.z;
  const long blockM = (long)by * 128;
  const long za = (long)bz * sAb, zb = (long)bz * sBb;
  const char* aP0 = A0 + za; const char* aP1 = A1 + za; const char* aP2 = A2 + za;
  const char* bP0 = B0 + zb; const char* bP1 = B1 + zb; const char* bP2 = B2 + zb;

  const long stgSw = ((tid & 7) ^ ((tid >> 3) & 7)) << 4;
  const long rA = (blockM + (tid >> 3)) * 1024 + stgSw;
  const long rB = ((long)(tid >> 3)) * 1024 + stgSw;

  f32x4 acc[4][8];
#pragma unroll
  for (int i = 0; i < 4; ++i)
#pragma unroll
    for (int j = 0; j < 8; ++j) acc[i][j] = (f32x4){0.f, 0.f, 0.f, 0.f};

  const int lr = l & 15, kg = l >> 4;
  const int s0 = ((kg ^ (lr & 7)) << 4);   // kh=0 slot byte; kh=1 = s0^64

  for (int t = 0; t < NT; ++t) {
    if (t) __syncthreads();               // all waves done reading tile t-1
    const char* pa = (t < 8 ? aP0 : t < 16 ? aP1 : aP2) + (((long)(t & 7)) << 7);
    const char* pb = (t < 8 ? bP0 : t < 16 ? bP1 : bP2) + (((long)(t & 7)) << 7);
#pragma unroll
    for (int g = 0; g < 2; ++g)
      gload16(pa + rA + (long)g * 65536, lds + g * 8192 + (tid << 4));
#pragma unroll
    for (int g = 0; g < 8; ++g)
      gload16(pb + rB + (long)g * 65536, lds + 16384 + g * 8192 + (tid << 4));
    __syncthreads();                      // drain + publish

    bf16x8 a[4][2], b[8][2];
#pragma unroll
    for (int mi = 0; mi < 4; ++mi) {
      const char* p = lds + ((wm * 64 + mi * 16 + lr) << 7);
      a[mi][0] = *(const bf16x8*)(p + s0);
      a[mi][1] = *(const bf16x8*)(p + (s0 ^ 64));
    }
#pragma unroll
    for (int nj = 0; nj < 8; ++nj) {
      const char* p = lds + 16384 + ((wn * 128 + nj * 16 + lr) << 7);
      b[nj][0] = *(const bf16x8*)(p + s0);
      b[nj][1] = *(const bf16x8*)(p + (s0 ^ 64));
    }
#pragma unroll
    for (int kh = 0; kh < 2; ++kh)
#pragma unroll
      for (int mi = 0; mi < 4; ++mi)
#pragma unroll
        for (int nj = 0; nj < 8; ++nj)
          acc[mi][nj] = __builtin_amdgcn_mfma_f32_16x16x32_bf16(
              b[nj][kh], a[mi][kh], acc[mi][nj], 0, 0, 0);
  }
  __syncthreads();                        // loop LDS dead -> reuse for tables

  float* red = (float*)lds;               // MODE0: [4][128]; MODE1: [4][128][2]
  // lane's rows: rowl[mi] = wm*64 + mi*16 + lr (local 0..127)
  // lane's cols: n = wn*128 + nj*16 + kg*4 + r
  const long rowG = (long)bz * 262144 + (blockM + wm * 64 + lr) * 512;
  const int nb = wn * 128 + (kg << 2);

  if (MODE == 0) {
    // v = sqrt(c^2+eps); row max
    float mx[4];
#pragma unroll
    for (int mi = 0; mi < 4; ++mi) {
      mx[mi] = -1e30f;
#pragma unroll
      for (int nj = 0; nj < 8; ++nj)
#pragma unroll
        for (int r = 0; r < 4; ++r) {
          float v = sqrtf(acc[mi][nj][r] * acc[mi][nj][r] + 1e-8f);
          acc[mi][nj][r] = v;
          mx[mi] = fmaxf(mx[mi], v);
        }
      mx[mi] = fmaxf(mx[mi], __shfl_xor(mx[mi], 16));
      mx[mi] = fmaxf(mx[mi], __shfl_xor(mx[mi], 32));
    }
    if (kg == 0)
#pragma unroll
      for (int mi = 0; mi < 4; ++mi)
        red[wn * 128 + wm * 64 + mi * 16 + lr] = mx[mi];
    __syncthreads();
    float gm[4], sm[4];
#pragma unroll
    for (int mi = 0; mi < 4; ++mi) {
      const int rl = wm * 64 + mi * 16 + lr;
      gm[mi] = fmaxf(fmaxf(red[rl], red[128 + rl]),
                     fmaxf(red[256 + rl], red[384 + rl]));
      sm[mi] = 0.f;
#pragma unroll
      for (int nj = 0; nj < 8; ++nj)
#pragma unroll
        for (int r = 0; r < 4; ++r) {
          float e = __expf(acc[mi][nj][r] - gm[mi]);
          acc[mi][nj][r] = e;
          sm[mi] += e;
        }
      sm[mi] += __shfl_xor(sm[mi], 16);
      sm[mi] += __shfl_xor(sm[mi], 32);
    }
    __syncthreads();                      // readers of max table done
    if (kg == 0)
#pragma unroll
      for (int mi = 0; mi < 4; ++mi)
        red[wn * 128 + wm * 64 + mi * 16 + lr] = sm[mi];
    __syncthreads();
#pragma unroll
    for (int mi = 0; mi < 4; ++mi) {
      const int rl = wm * 64 + mi * 16 + lr;
      const float inv = 1.0f / (red[rl] + red[128 + rl] + red[256 + rl] + red[384 + rl]);
      const long base = rowG + (long)mi * 16 * 512;
#pragma unroll
      for (int nj = 0; nj < 8; ++nj) {
        union { u16 h[4]; uint2 u; } p;
#pragma unroll
        for (int r = 0; r < 4; ++r) p.h[r] = f2bf(acc[mi][nj][r] * inv);
        *(uint2*)(outU + base + nb + nj * 16) = p.u;
      }
    }
  } else {
    // x1 = resid + c ; write f32 ; LayerNorm stats
    float s[4], q[4];
#pragma unroll
    for (int mi = 0; mi < 4; ++mi) {
      const long base = rowG + (long)mi * 16 * 512;
      s[mi] = 0.f; q[mi] = 0.f;
#pragma unroll
      for (int nj = 0; nj < 8; ++nj) {
        const long idx = base + nb + nj * 16;
        f32x4 rd = *(const f32x4*)(resid + idx);
#pragma unroll
        for (int r = 0; r < 4; ++r) {
          float x1 = rd[r] + acc[mi][nj][r];
          acc[mi][nj][r] = x1;
          s[mi] += x1;
          q[mi] += x1 * x1;
        }
        *(f32x4*)(outF + idx) = acc[mi][nj];
      }
      s[mi] += __shfl_xor(s[mi], 16);
      s[mi] += __shfl_xor(s[mi], 32);
      q[mi] += __shfl_xor(q[mi], 16);
      q[mi] += __shfl_xor(q[mi], 32);
    }
    if (kg == 0)
#pragma unroll
      for (int mi = 0; mi < 4; ++mi) {
        const int rl = wm * 64 + mi * 16 + lr;
        red[(wn * 128 + rl) * 2]     = s[mi];
        red[(wn * 128 + rl) * 2 + 1] = q[mi];
      }
    __syncthreads();
#pragma unroll
    for (int mi = 0; mi < 4; ++mi) {
      const int rl = wm * 64 + mi * 16 + lr;
      float S = red[rl * 2] + red[(128 + rl) * 2] + red[(256 + rl) * 2] + red[(384 + rl) * 2];
      float Q = red[rl * 2 + 1] + red[(128 + rl) * 2 + 1] + red[(256 + rl) * 2 + 1] + red[(384 + rl) * 2 + 1];
      const float mu = S * (1.0f / 512.0f);
      const float var = Q * (1.0f / 512.0f) - mu * mu;
      const float rs = rsqrtf(var + 1e-5f);
      const long base = rowG + (long)mi * 16 * 512;
#pragma unroll
      for (int nj = 0; nj < 8; ++nj) {
        const int n = nb + nj * 16;
        f32x4 g4 = *(const f32x4*)(g2 + n);
        f32x4 b4 = *(const f32x4*)(b2 + n);
        union { u16 h[4]; uint2 u; } p;
#pragma unroll
        for (int r = 0; r < 4; ++r)
          p.h[r] = f2bf((acc[mi][nj][r] - mu) * rs * g4[r] + b4[r]);
        *(uint2*)(outU + base + n) = p.u;
      }
    }
  }
}

// ---------- launch ----------
extern "C" void kernel_launch(void* const* d_in, const int* in_sizes, int n_in,
                              void* d_out, int out_size, void* d_ws, size_t ws_size,
                              hipStream_t stream)
{
  const float* x   = (const float*)d_in[0];
  const float* g1  = (const float*)d_in[1];
  const float* be1 = (const float*)d_in[2];
  const float* Wv  = (const float*)d_in[3];
  const float* Ww  = (const float*)d_in[4];
  const float* g2  = (const float*)d_in[5];
  const float* be2 = (const float*)d_in[6];
  const float* W1  = (const float*)d_in[7];
  const float* b1  = (const float*)d_in[8];
  const float* W2  = (const float*)d_in[9];
  const float* b2  = (const float*)d_in[10];
  float* out = (float*)d_out;

  char* ws = (char*)d_ws;
  // B=64, T=E=512, H=2048, M=B*T=32768. Lifetimes allow heavy aliasing.
  u16* inp_hi  = (u16*)(ws);                 // [0,32M)   LN1 -> vx/proj/scores
  u16* inp_lo  = (u16*)(ws + 33554432);      // [32,64M)  LN1 -> proj/scores
  u16* proj_hi = (u16*)(ws + 67108864);      // [64,96M)  proj -> scores
  u16* proj_lo = (u16*)(ws + 100663296);     // [96,128M) proj -> scores
  u16* attn    = (u16*)(ws + 134217728);     // [128,160M) scoresSM -> tLN
  u16* vx      = proj_lo;                    // alias: vx GEMM runs post-scores
  u16* h_in    = inp_hi;                     // alias: written by tLN after inp dead
  u16* h_mid   = (u16*)(ws + 33554432);      // [32,160M): attn/vx/proj dead by MLP1
  char* wb = ws + 201326592;                 // weights live whole run
  u16* WvT  = (u16*)(wb);
  u16* WwTh = (u16*)(wb + 524288);
  u16* WwTl = (u16*)(wb + 1048576);
  u16* W1T  = (u16*)(wb + 1572864);
  u16* W2T  = (u16*)(wb + 3670016);

  // weight transposes (f32 -> bf16, K-contiguous for NT GEMM)
  transpose_split_kernel<<<dim3(16, 16), 256, 0, stream>>>(Wv, WvT, nullptr, 512, 512);
  transpose_split_kernel<<<dim3(16, 16), 256, 0, stream>>>(Ww, WwTh, WwTl, 512, 512);
  transpose_split_kernel<<<dim3(64, 16), 256, 0, stream>>>(W1, W1T, nullptr, 512, 2048);
  transpose_split_kernel<<<dim3(16, 64), 256, 0, stream>>>(W2, W2T, nullptr, 2048, 512);

  // LN1: x -> inp hi/lo
  ln_split_kernel<<<8192, 256, 0, stream>>>(x, g1, be1, inp_hi, inp_lo);

  // proj = inp@Ww, split 3-term via K-cat: [ih,il,ih] . [Wh,Wh,Wl], K'=1536
  gemm8<1><<<dim3(2, 128, 1), 512, 0, stream>>>(
      (const char*)inp_hi, (const char*)inp_lo, (const char*)inp_hi, (const char*)inp_hi,
      (const char*)WwTh, (const char*)WwTh, (const char*)WwTl, (const char*)WwTl,
      512, 24, 1024, 1024, 0, 0, 0,
      nullptr, proj_hi, proj_lo, nullptr, nullptr);

  // attn = softmax(sqrt(scores^2+eps)), scores split: [ph,ph,pl].[ih,il,ih]
  // fused: full row per block, no f32 scores buffer, no softmax kernel
  gemm_row<0><<<dim3(1, 4, 64), 512, 0, stream>>>(
      (const char*)proj_hi, (const char*)proj_hi, (const char*)proj_lo,
      (const char*)inp_hi, (const char*)inp_lo, (const char*)inp_hi,
      24, 524288, 524288,
      attn, nullptr, nullptr, nullptr, nullptr);

  // vx = sqrt((inp@Wv)^2+eps) (into dead proj_lo)
  gemm8<0><<<dim3(2, 128, 1), 512, 0, stream>>>(
      (const char*)inp_hi, (const char*)inp_hi, (const char*)inp_hi, (const char*)inp_hi,
      (const char*)WvT, (const char*)WvT, (const char*)WvT, (const char*)WvT,
      512, 8, 1024, 1024, 0, 0, 0,
      nullptr, vx, nullptr, nullptr, nullptr);

  // x1 = x + attn@vx^T -> out (f32) ; h_in = LN2(x1) bf16   (fused)
  gemm_row<1><<<dim3(1, 4, 64), 512, 0, stream>>>(
      (const char*)attn, (const char*)attn, (const char*)attn,
      (const char*)vx, (const char*)vx, (const char*)vx,
      8, 524288, 524288,
      h_in, out, x, g2, be2);

  // h_mid = gelu(h_in@W1 + b1)
  gemm8<4><<<dim3(8, 128, 1), 512, 0, stream>>>(
      (const char*)h_in, (const char*)h_in, (const char*)h_in, (const char*)h_in,
      (const char*)W1T, (const char*)W1T, (const char*)W1T, (const char*)W1T,
      2048, 8, 1024, 1024, 0, 0, 0,
      nullptr, h_mid, nullptr, nullptr, b1);

  // out = x1 + h_mid@W2 + b2  (K=2048 via 4 contiguous parts)
  gemm8<5><<<dim3(2, 128, 1), 512, 0, stream>>>(
      (const char*)h_mid, (const char*)h_mid + 1024, (const char*)h_mid + 2048, (const char*)h_mid + 3072,
      (const char*)W2T, (const char*)W2T + 1024, (const char*)W2T + 2048, (const char*)W2T + 3072,
      512, 32, 4096, 4096, 0, 0, 0,
      out, nullptr, nullptr, out, b2);
}

// Round 10
// 377.345 us; speedup vs baseline: 1.3290x; 1.2576x over previous
//
#include <hip/hip_runtime.h>

using f16x8 = __attribute__((ext_vector_type(8))) _Float16;
using f32x4 = __attribute__((ext_vector_type(4))) float;
using u16 = unsigned short;
using u32 = unsigned int;

// ---------- helpers ----------
__device__ __forceinline__ u16 f2h(float f) {           // RNE f32->fp16 (v_cvt)
  union { _Float16 h; u16 u; } c;
  c.h = (_Float16)f;
  return c.u;
}
__device__ __forceinline__ uint4 pack8(const u16* h) {
  uint4 r;
  r.x = (u32)h[0] | ((u32)h[1] << 16);
  r.y = (u32)h[2] | ((u32)h[3] << 16);
  r.z = (u32)h[4] | ((u32)h[5] << 16);
  r.w = (u32)h[6] | ((u32)h[7] << 16);
  return r;
}
__device__ __forceinline__ float gelu_fast(float x) {   // == 0.5x(1+tanh(u)) exactly
  float u2 = 1.5957691216057308f * (x + 0.044715f * x * x * x);  // 2u
  return x / (1.0f + __expf(-u2));
}
__device__ __forceinline__ void gload16(const void* g, void* l) {
  __builtin_amdgcn_global_load_lds(
      (const __attribute__((address_space(1))) void*)g,
      (__attribute__((address_space(3))) void*)l, 16, 0, 0);
}

// ---------- weight transpose: [R,C] f32 -> [C,R] fp16 ----------
__global__ __launch_bounds__(256) void transpose_f16_kernel(
    const float* __restrict__ in, u16* __restrict__ out, int R, int C)
{
  __shared__ float t[32][33];
  const int lx = threadIdx.x & 31, ly = threadIdx.x >> 5;
  const int c0 = blockIdx.x << 5, r0 = blockIdx.y << 5;
  for (int i = ly; i < 32; i += 8)
    t[i][lx] = in[(long)(r0 + i) * C + c0 + lx];
  __syncthreads();
  for (int i = ly; i < 32; i += 8)
    out[(long)(c0 + i) * R + r0 + lx] = f2h(t[lx][i]);
}

// ---------- LayerNorm over rows of 512 f32 -> fp16 ----------
__global__ __launch_bounds__(256) void ln_f16_kernel(
    const float* __restrict__ x, const float* __restrict__ gamma,
    const float* __restrict__ beta, u16* __restrict__ outH)
{
  const int row  = (blockIdx.x << 2) + (threadIdx.x >> 6);
  const int lane = threadIdx.x & 63;
  const float* xr = x + (long)row * 512 + lane * 8;
  float v[8];
  *(float4*)&v[0] = *(const float4*)xr;
  *(float4*)&v[4] = *(const float4*)(xr + 4);
  float s = 0.f;
#pragma unroll
  for (int j = 0; j < 8; ++j) s += v[j];
#pragma unroll
  for (int o = 32; o; o >>= 1) s += __shfl_xor(s, o);
  const float mu = s * (1.0f / 512.0f);
  float q = 0.f;
#pragma unroll
  for (int j = 0; j < 8; ++j) { float d = v[j] - mu; q += d * d; }
#pragma unroll
  for (int o = 32; o; o >>= 1) q += __shfl_xor(q, o);
  const float rs = rsqrtf(q * (1.0f / 512.0f) + 1e-5f);
  float gv[8], bv[8];
  *(float4*)&gv[0] = *(const float4*)(gamma + lane * 8);
  *(float4*)&gv[4] = *(const float4*)(gamma + lane * 8 + 4);
  *(float4*)&bv[0] = *(const float4*)(beta + lane * 8);
  *(float4*)&bv[4] = *(const float4*)(beta + lane * 8 + 4);
  u16 hs[8];
#pragma unroll
  for (int j = 0; j < 8; ++j)
    hs[j] = f2h((v[j] - mu) * rs * gv[j] + bv[j]);
  *(uint4*)(outH + (long)row * 512 + lane * 8) = pack8(hs);
}

// ---------- row softmax over 512 f32 -> fp16 ----------
__global__ __launch_bounds__(256) void softmax_kernel(
    const float* __restrict__ scores, u16* __restrict__ attn)
{
  const int row  = (blockIdx.x << 2) + (threadIdx.x >> 6);
  const int lane = threadIdx.x & 63;
  const float* sr = scores + (long)row * 512 + lane * 8;
  float v[8];
  *(float4*)&v[0] = *(const float4*)sr;
  *(float4*)&v[4] = *(const float4*)(sr + 4);
  float m = v[0];
#pragma unroll
  for (int j = 1; j < 8; ++j) m = fmaxf(m, v[j]);
#pragma unroll
  for (int o = 32; o; o >>= 1) m = fmaxf(m, __shfl_xor(m, o));
  float e[8], s = 0.f;
#pragma unroll
  for (int j = 0; j < 8; ++j) { e[j] = __expf(v[j] - m); s += e[j]; }
#pragma unroll
  for (int o = 32; o; o >>= 1) s += __shfl_xor(s, o);
  const float inv = 1.0f / s;
  u16 h[8];
#pragma unroll
  for (int j = 0; j < 8; ++j) h[j] = f2h(e[j] * inv);
  *(uint4*)(attn + (long)row * 512 + lane * 8) = pack8(h);
}

// ---------- 256x256 8-wave NT GEMM, BK=64, fp16 (r7 structure) ----------
// C[m,n] = sum_k A[m,k]*B[n,k]. K in NT tiles of 64; tile t uses part (t>>3)
// (part pointers enable K=2048 via 4 contiguous chunks for MLP2).
// LDS 128KB: A regions (d,h) at d*32768+h*16384; B at +65536. Row r at
// r*128B; 16B K-slot s XOR-swizzled to s^(r&7) (pre-swizzled global source,
// LDS-linear global_load_lds dest, swizzled ds_read — rule #21).
// Loop: issue tile t+1's 8 global_load_lds into buffer d^1, then 24
// ds_read_b128 + 64 MFMA (f16), one __syncthreads() per tile.
// XCD-chunked block swizzle; swapped-operand MFMA -> wide stores.
// EPI: 0 fp16 sqrt(v^2+eps); 1 fp16 v; 2 f32 sqrt(v^2+eps); 3 resid+v;
//      4 fp16 gelu(v+bias); 5 resid+v+bias.
template<int EPI>
__global__ __launch_bounds__(512) void gemm8(
    const char* A0, const char* A1, const char* A2, const char* A3,
    const char* B0, const char* B1, const char* B2, const char* B3,
    int N, int NT, int ldAb, int ldBb,
    long sAb, long sBb, long sC,
    float* __restrict__ outF, u16* __restrict__ outU,
    const float* __restrict__ resid, const float* __restrict__ bias)
{
  __shared__ __align__(16) char lds[131072];
  const int tid = threadIdx.x;
  const int w = tid >> 6, l = tid & 63;
  const int wm = w >> 2, wn = w & 3;

  // XCD-chunked block swizzle (total %8 == 0 for all our launches)
  const int gx = gridDim.x, gy = gridDim.y;
  int flat = ((int)blockIdx.z * gy + (int)blockIdx.y) * gx + (int)blockIdx.x;
  const int total = gx * gy * (int)gridDim.z;
  flat = (flat & 7) * (total >> 3) + (flat >> 3);
  const int bx = flat % gx;
  int rem = flat / gx;
  const int by = rem % gy, bz = rem / gy;

  const long blockM = (long)by * 256;
  const long blockN = (long)bx * 256;
  const long za = (long)bz * sAb;
  const long zb = (long)bz * sBb;
  const char* a0p = A0 + za; const char* a1p = A1 + za;
  const char* a2p = A2 + za; const char* a3p = A3 + za;
  const char* b0p = B0 + zb; const char* b1p = B1 + zb;
  const char* b2p = B2 + zb; const char* b3p = B3 + zb;

  auto partA = [&](int t) { return t < 8 ? a0p : t < 16 ? a1p : t < 24 ? a2p : a3p; };
  auto partB = [&](int t) { return t < 8 ? b0p : t < 16 ? b1p : t < 24 ? b2p : b3p; };

  const long stgSw = ((tid & 7) ^ ((tid >> 3) & 7)) << 4;
  const long raA = (blockM + (tid >> 3)) * (long)ldAb + stgSw;
  const long raB = (blockN + (tid >> 3)) * (long)ldBb + stgSw;
  auto stageA = [&](int t, int h) {
    const char* s = partA(t) + (((long)(t & 7)) << 7) + raA + (long)h * 128 * ldAb;
    char* dptr = lds + ((t & 1) << 15) + (h << 14) + (tid << 4);
    gload16(s, dptr);
    gload16(s + (long)64 * ldAb, dptr + 8192);
  };
  auto stageB = [&](int t, int h) {
    const char* s = partB(t) + (((long)(t & 7)) << 7) + raB + (long)h * 128 * ldBb;
    char* dptr = lds + 65536 + ((t & 1) << 15) + (h << 14) + (tid << 4);
    gload16(s, dptr);
    gload16(s + (long)64 * ldBb, dptr + 8192);
  };

  f32x4 acc[8][4];
#pragma unroll
  for (int i = 0; i < 8; ++i)
#pragma unroll
    for (int j = 0; j < 4; ++j) acc[i][j] = (f32x4){0.f, 0.f, 0.f, 0.f};

  const int lr = l & 15, kg = l >> 4;
  const int xs = kg ^ (l & 7);
  const int po0 = (lr << 7) + (xs << 4);
  const int po1 = (lr << 7) + ((xs ^ 4) << 4);
  const char* aL = lds + (wm << 14);
  const char* bL = lds + 65536 + ((wn >> 1) << 14) + ((wn & 1) << 13);

  f16x8 a[4], bk0[4], bk1[4];
  auto readA = [&](const char* p) {
#pragma unroll
    for (int mf = 0; mf < 4; ++mf) a[mf] = *(const f16x8*)(p + (mf << 11));
  };
  auto readB = [&](f16x8* d, const char* p) {
#pragma unroll
    for (int nf = 0; nf < 4; ++nf) d[nf] = *(const f16x8*)(p + (nf << 11));
  };

#define MFMA16(MH, BK)                                                        \
  do {                                                                        \
    _Pragma("unroll")                                                         \
    for (int mf = 0; mf < 4; ++mf)                                            \
      _Pragma("unroll")                                                       \
      for (int nf = 0; nf < 4; ++nf)                                          \
        acc[MH * 4 + mf][nf] = __builtin_amdgcn_mfma_f32_16x16x32_f16(        \
            BK[nf], a[mf], acc[MH * 4 + mf][nf], 0, 0, 0);                    \
  } while (0)

  stageA(0, 0); stageA(0, 1); stageB(0, 0); stageB(0, 1);
  __syncthreads();

  for (int t = 0; t < NT; ++t) {
    const int d = t & 1;
    const char* aD = aL + (d << 15);
    const char* bD = bL + (d << 15);
    if (t + 1 < NT) {
      stageA(t + 1, 0); stageA(t + 1, 1); stageB(t + 1, 0); stageB(t + 1, 1);
    }
    readA(aD + po0);
    readB(bk0, bD + po0);
    MFMA16(0, bk0);
    readA(aD + po1);
    readB(bk1, bD + po1);
    MFMA16(0, bk1);
    readA(aD + 8192 + po0);
    MFMA16(1, bk0);
    readA(aD + 8192 + po1);
    MFMA16(1, bk1);
    if (t + 1 < NT) __syncthreads();
  }
#undef MFMA16

  const long cb = (long)bz * sC;
  const int m0 = (int)blockM + wm * 128 + lr;
  const int n0 = (int)blockN + wn * 64 + (kg << 2);
#pragma unroll
  for (int mi = 0; mi < 8; ++mi)
#pragma unroll
    for (int ni = 0; ni < 4; ++ni) {
      const int m = m0 + (mi << 4);
      const int n = n0 + (ni << 4);
      const long idx = cb + (long)m * N + n;
      f32x4 v = acc[mi][ni];
      if (EPI == 0) {
        union { u16 h[4]; uint2 u; } p;
#pragma unroll
        for (int r = 0; r < 4; ++r) p.h[r] = f2h(sqrtf(v[r] * v[r] + 1e-8f));
        *(uint2*)(outU + idx) = p.u;
      } else if (EPI == 1) {
        union { u16 h[4]; uint2 u; } p;
#pragma unroll
        for (int r = 0; r < 4; ++r) p.h[r] = f2h(v[r]);
        *(uint2*)(outU + idx) = p.u;
      } else if (EPI == 2) {
        f32x4 o;
#pragma unroll
        for (int r = 0; r < 4; ++r) o[r] = sqrtf(v[r] * v[r] + 1e-8f);
        *(f32x4*)(outF + idx) = o;
      } else if (EPI == 3) {
        f32x4 rd = *(const f32x4*)(resid + idx);
#pragma unroll
        for (int r = 0; r < 4; ++r) rd[r] += v[r];
        *(f32x4*)(outF + idx) = rd;
      } else if (EPI == 4) {
        f32x4 bb = *(const f32x4*)(bias + n);
        union { u16 h[4]; uint2 u; } p;
#pragma unroll
        for (int r = 0; r < 4; ++r) p.h[r] = f2h(gelu_fast(v[r] + bb[r]));
        *(uint2*)(outU + idx) = p.u;
      } else {
        f32x4 rd = *(const f32x4*)(resid + idx);
        f32x4 bb = *(const f32x4*)(bias + n);
#pragma unroll
        for (int r = 0; r < 4; ++r) rd[r] += v[r] + bb[r];
        *(f32x4*)(outF + idx) = rd;
      }
    }
}

// ---------- launch ----------
extern "C" void kernel_launch(void* const* d_in, const int* in_sizes, int n_in,
                              void* d_out, int out_size, void* d_ws, size_t ws_size,
                              hipStream_t stream)
{
  const float* x   = (const float*)d_in[0];
  const float* g1  = (const float*)d_in[1];
  const float* be1 = (const float*)d_in[2];
  const float* Wv  = (const float*)d_in[3];
  const float* Ww  = (const float*)d_in[4];
  const float* g2  = (const float*)d_in[5];
  const float* be2 = (const float*)d_in[6];
  const float* W1  = (const float*)d_in[7];
  const float* b1  = (const float*)d_in[8];
  const float* W2  = (const float*)d_in[9];
  const float* b2  = (const float*)d_in[10];
  float* out = (float*)d_out;

  char* ws = (char*)d_ws;
  // B=64, T=E=512, H=2048, M=B*T=32768. fp16 single-pass everywhere.
  u16* inp    = (u16*)(ws);                  // [0,32M)    LN1 -> proj/scores/vx
  u16* proj   = (u16*)(ws + 33554432);       // [32,64M)   proj -> scores
  float* scores = (float*)(ws + 67108864);   // [64,128M)  scores -> softmax
  u16* vx     = (u16*)(ws + 134217728);      // [128,160M) vx -> t
  u16* attn   = proj;                        // alias: written after proj read
  u16* h_in   = inp;                         // alias: written after inp dead
  u16* h_mid  = (u16*)(ws + 33554432);       // [32,160M): proj/scores/vx dead
  char* wb = ws + 167772160;                 // weights live whole run
  u16* WvT = (u16*)(wb);
  u16* WwT = (u16*)(wb + 524288);
  u16* W1T = (u16*)(wb + 1048576);
  u16* W2T = (u16*)(wb + 3145728);
  // total ws used: ~165 MB

  // weight transposes (f32 -> fp16, K-contiguous for NT GEMM)
  transpose_f16_kernel<<<dim3(16, 16), 256, 0, stream>>>(Wv, WvT, 512, 512);
  transpose_f16_kernel<<<dim3(16, 16), 256, 0, stream>>>(Ww, WwT, 512, 512);
  transpose_f16_kernel<<<dim3(64, 16), 256, 0, stream>>>(W1, W1T, 512, 2048);
  transpose_f16_kernel<<<dim3(16, 64), 256, 0, stream>>>(W2, W2T, 2048, 512);

  // LN1: x -> inp fp16
  ln_f16_kernel<<<8192, 256, 0, stream>>>(x, g1, be1, inp);

  // proj = inp@Ww (fp16 single-pass)
  gemm8<1><<<dim3(2, 128, 1), 512, 0, stream>>>(
      (const char*)inp, (const char*)inp, (const char*)inp, (const char*)inp,
      (const char*)WwT, (const char*)WwT, (const char*)WwT, (const char*)WwT,
      512, 8, 1024, 1024, 0, 0, 0,
      nullptr, proj, nullptr, nullptr);

  // scores[b,i,j] = sqrt((proj_i . inp_j)^2+eps) -> f32 (batched)
  gemm8<2><<<dim3(2, 2, 64), 512, 0, stream>>>(
      (const char*)proj, (const char*)proj, (const char*)proj, (const char*)proj,
      (const char*)inp, (const char*)inp, (const char*)inp, (const char*)inp,
      512, 8, 1024, 1024, 524288, 524288, 262144,
      scores, nullptr, nullptr, nullptr);

  // softmax rows -> attn fp16 (into dead proj)
  softmax_kernel<<<8192, 256, 0, stream>>>(scores, attn);

  // vx = sqrt((inp@Wv)^2+eps) fp16
  gemm8<0><<<dim3(2, 128, 1), 512, 0, stream>>>(
      (const char*)inp, (const char*)inp, (const char*)inp, (const char*)inp,
      (const char*)WvT, (const char*)WvT, (const char*)WvT, (const char*)WvT,
      512, 8, 1024, 1024, 0, 0, 0,
      nullptr, vx, nullptr, nullptr);

  // x1 = x + attn@vx^T -> d_out f32 (batched)
  gemm8<3><<<dim3(2, 2, 64), 512, 0, stream>>>(
      (const char*)attn, (const char*)attn, (const char*)attn, (const char*)attn,
      (const char*)vx, (const char*)vx, (const char*)vx, (const char*)vx,
      512, 8, 1024, 1024, 524288, 524288, 262144,
      out, nullptr, x, nullptr);

  // LN2: x1 -> h_in fp16 (into dead inp)
  ln_f16_kernel<<<8192, 256, 0, stream>>>(out, g2, be2, h_in);

  // h_mid = gelu(h_in@W1 + b1) fp16
  gemm8<4><<<dim3(8, 128, 1), 512, 0, stream>>>(
      (const char*)h_in, (const char*)h_in, (const char*)h_in, (const char*)h_in,
      (const char*)W1T, (const char*)W1T, (const char*)W1T, (const char*)W1T,
      2048, 8, 1024, 1024, 0, 0, 0,
      nullptr, h_mid, nullptr, b1);

  // out = x1 + h_mid@W2 + b2  (K=2048 via 4 contiguous parts)
  gemm8<5><<<dim3(2, 128, 1), 512, 0, stream>>>(
      (const char*)h_mid, (const char*)h_mid + 1024, (const char*)h_mid + 2048, (const char*)h_mid + 3072,
      (const char*)W2T, (const char*)W2T + 1024, (const char*)W2T + 2048, (const char*)W2T + 3072,
      512, 32, 4096, 4096, 0, 0, 0,
      out, nullptr, out, b2);
}